// Round 12
// baseline (163.376 us; speedup 1.0000x reference)
//
#include <hip/hip_runtime.h>

constexpr int N_NODES = 100000;
constexpr int F1 = 64;   // IN_DIM == HID_DIM
constexpr int F2 = 16;   // OUT_DIM
constexpr int SH = 7;                             // bin = dst >> 7
constexpr int NPB = 128;                          // nodes per bin
constexpr int NBINS = (N_NODES + NPB - 1) / NPB;  // 782
constexpr int CAPB = 2560;                        // mean 2176 (incl self), +8.5 sigma
constexpr int TILE = 4096;                        // edges per k_bin block

// bf16 helpers (RNE)
static __device__ __forceinline__ unsigned short f2bf(float f) {
    unsigned int u = __float_as_uint(f);
    unsigned int r = (u + 0x7fffu + ((u >> 16) & 1u)) >> 16;
    return (unsigned short)r;
}
static __device__ __forceinline__ float bf2f(unsigned short b) {
    return __uint_as_float(((unsigned int)b) << 16);
}
static __device__ __forceinline__ float lo16(unsigned int u) { return __uint_as_float(u << 16); }
static __device__ __forceinline__ float hi16(unsigned int u) { return __uint_as_float(u & 0xFFFF0000u); }

// ---------------- pass 1: coarse binning, self-loops injected as edges ----------------
__global__ __launch_bounds__(512) void k_bin(const int* __restrict__ src,
                                             const int* __restrict__ dst, int E,
                                             unsigned int* __restrict__ gcnt,
                                             unsigned int* __restrict__ entries) {
    __shared__ unsigned int cnt[NBINS];
    __shared__ unsigned int cur[NBINS];
    int tid = threadIdx.x;
    int base = blockIdx.x * TILE;
    int end = min(base + TILE, E + N_NODES);
    for (int i = tid; i < NBINS; i += 512) cnt[i] = 0;
    __syncthreads();
    for (int e = base + tid; e < end; e += 512) {
        int d = (e < E) ? dst[e] : (e - E);
        atomicAdd(&cnt[d >> SH], 1u);
    }
    __syncthreads();
    for (int i = tid; i < NBINS; i += 512) {
        unsigned int c = cnt[i];
        cur[i] = (unsigned int)i * CAPB + (c ? atomicAdd(&gcnt[i], c) : 0u);
    }
    __syncthreads();
    for (int e = base + tid; e < end; e += 512) {
        int d, s;
        if (e < E) { d = dst[e]; s = src[e]; }
        else       { d = e - E;  s = d; }
        int bb = d >> SH;
        unsigned int p = atomicAdd(&cur[bb], 1u);
        if (p - (unsigned int)bb * CAPB < CAPB)
            entries[p] = (unsigned int)s | ((unsigned int)(d & (NPB - 1)) << 17);
    }
}

// ---------------- CSR build: hist -> scan -> scatter + dinv + absolute node ranges ----------------
__global__ __launch_bounds__(512) void k_csr(const unsigned int* __restrict__ gcnt,
                                             const unsigned int* __restrict__ entries,
                                             uint2* __restrict__ nrange,
                                             unsigned int* __restrict__ sorted,
                                             float* __restrict__ dinv) {
    __shared__ unsigned int ncnt[NPB];
    __shared__ unsigned int noff[NPB + 1];
    __shared__ unsigned int cur[NPB];
    int tid = threadIdx.x;
    int b = blockIdx.x;
    unsigned int cntE = gcnt[b]; if (cntE > CAPB) cntE = CAPB;
    unsigned int base = (unsigned int)b * CAPB;
    if (tid < NPB) ncnt[tid] = 0;
    __syncthreads();
    for (unsigned int e = tid; e < cntE; e += 512)
        atomicAdd(&ncnt[entries[base + e] >> 17], 1u);
    __syncthreads();
    if (tid < NPB) cur[tid] = ncnt[tid];
    __syncthreads();
    for (int ofs = 1; ofs < NPB; ofs <<= 1) {
        unsigned int v = (tid < NPB && tid >= ofs) ? cur[tid - ofs] : 0u;
        __syncthreads();
        if (tid < NPB) cur[tid] += v;
        __syncthreads();
    }
    if (tid < NPB) noff[tid + 1] = cur[tid];
    if (tid == 0) noff[0] = 0;
    __syncthreads();
    if (tid < NPB) {
        int node = b * NPB + tid;
        if (node < N_NODES) {
            dinv[node] = rsqrtf((float)max(ncnt[tid], 1u));  // count includes self-edge
            nrange[node] = make_uint2(base + noff[tid], base + noff[tid + 1]);
        }
        cur[tid] = noff[tid];
    }
    __syncthreads();
    for (unsigned int e = tid; e < cntE; e += 512) {
        unsigned int v = entries[base + e];
        unsigned int p = atomicAdd(&cur[v >> 17], 1u);
        sorted[base + p] = v & 0x1FFFFu;
    }
}

// ---------------- hs = bf16((x @ W1) * dinv[row]) — register-tiled 4x4 ----------------
__global__ __launch_bounds__(256) void k_xw1(const float* __restrict__ x,
                                             const float* __restrict__ W,
                                             const float* __restrict__ dinv,
                                             unsigned short* __restrict__ hs) {
    constexpr int XS = 68;
    __shared__ float Ws[64 * 64];
    __shared__ float xs[64 * XS];
    int tid = threadIdx.x;
    int r0 = blockIdx.x * 64;
    for (int i = tid; i < 1024; i += 256) {
        int k = i >> 4, c4 = (i & 15) << 2;
        *(float4*)&Ws[k * 64 + c4] = *(const float4*)&W[k * 64 + c4];
    }
    for (int i = tid; i < 1024; i += 256) {
        int rr = i >> 4, c4 = (i & 15) << 2;
        int r = r0 + rr;
        float4 v = make_float4(0.f, 0.f, 0.f, 0.f);
        if (r < N_NODES) v = *(const float4*)&x[(size_t)r * 64 + c4];
        *(float4*)&xs[rr * XS + c4] = v;
    }
    __syncthreads();
    int tx = tid & 15, ty = tid >> 4;
    int c0 = tx << 2, rb = ty << 2;
    float acc[4][4] = {};
#pragma unroll 8
    for (int k = 0; k < 64; ++k) {
        float4 w = *(float4*)&Ws[k * 64 + c0];
        float x0 = xs[(rb + 0) * XS + k];
        float x1 = xs[(rb + 1) * XS + k];
        float x2 = xs[(rb + 2) * XS + k];
        float x3 = xs[(rb + 3) * XS + k];
        acc[0][0] += x0 * w.x; acc[0][1] += x0 * w.y; acc[0][2] += x0 * w.z; acc[0][3] += x0 * w.w;
        acc[1][0] += x1 * w.x; acc[1][1] += x1 * w.y; acc[1][2] += x1 * w.z; acc[1][3] += x1 * w.w;
        acc[2][0] += x2 * w.x; acc[2][1] += x2 * w.y; acc[2][2] += x2 * w.z; acc[2][3] += x2 * w.w;
        acc[3][0] += x3 * w.x; acc[3][1] += x3 * w.y; acc[3][2] += x3 * w.z; acc[3][3] += x3 * w.w;
    }
#pragma unroll
    for (int i = 0; i < 4; ++i) {
        int r = r0 + rb + i;
        if (r >= N_NODES) break;
        float dv = dinv[r];
        ushort4 p;
        p.x = f2bf(acc[i][0] * dv);
        p.y = f2bf(acc[i][1] * dv);
        p.z = f2bf(acc[i][2] * dv);
        p.w = f2bf(acc[i][3] * dv);
        *(ushort4*)&hs[(size_t)r * 64 + c0] = p;
    }
}

// ---------------- layer-1 agg FUSED with layer-2 projection ----------------
// wave per node: gather-sum hs -> conv1 row (fp32, lanes 0-15 x 4 feats)
// -> +b1, relu, row@W2*dinv -> h2s directly (out1 never materialized)
__global__ __launch_bounds__(256) void k_agg1f(const uint2* __restrict__ nrange,
                                               const unsigned int* __restrict__ sorted,
                                               const unsigned short* __restrict__ hs,
                                               const float* __restrict__ dinv,
                                               const float* __restrict__ b1,
                                               const float* __restrict__ W2,
                                               unsigned short* __restrict__ h2s) {
    __shared__ float W2s[64 * 17];   // stride 17: 2-way bank aliasing (free)
    __shared__ float b1s[64];
    __shared__ float rowbuf[4][64];  // per-wave conv1 row
    int tid = threadIdx.x;
    for (int i = tid; i < 1024; i += 256) W2s[(i >> 4) * 17 + (i & 15)] = W2[i];
    if (tid < 64) b1s[tid] = b1[tid];
    __syncthreads();
    int gw = (blockIdx.x * 256 + tid) >> 6;  // node
    if (gw >= N_NODES) return;
    int wv = (tid >> 6) & 3;
    int lane = tid & 63;
    int slot = lane >> 4, t = lane & 15;  // lane covers feats [4t,4t+4) of edge-slot `slot`
    const uint2* hs8 = (const uint2*)hs;  // row = 16 x uint2
    uint2 rg = nrange[gw];
    float a0 = 0.f, a1 = 0.f, a2 = 0.f, a3 = 0.f;
    for (unsigned int j = rg.x; j < rg.y; j += 64) {
        unsigned int cnt = rg.y - j; if (cnt > 64u) cnt = 64u;
        unsigned int idx = (unsigned)lane < cnt ? sorted[j + lane] : 0u;  // 1 VMEM / 64 edges
        unsigned int rounds = (cnt + 3u) >> 2;
#pragma unroll 4
        for (unsigned int r = 0; r < rounds; ++r) {
            unsigned int sl = (r << 2) + (unsigned)slot;
            unsigned int myidx = (unsigned int)__shfl((int)idx, (int)sl);
            if (sl < cnt) {
                uint2 u = hs8[(size_t)myidx * 16 + t];
                a0 += lo16(u.x); a1 += hi16(u.x);
                a2 += lo16(u.y); a3 += hi16(u.y);
            }
        }
    }
    // reduce across 4 edge-slots
    a0 += __shfl_xor(a0, 16); a1 += __shfl_xor(a1, 16);
    a2 += __shfl_xor(a2, 16); a3 += __shfl_xor(a3, 16);
    a0 += __shfl_xor(a0, 32); a1 += __shfl_xor(a1, 32);
    a2 += __shfl_xor(a2, 32); a3 += __shfl_xor(a3, 32);
    float dv = dinv[gw];
    if (slot == 0) {
        // conv1 out = acc*dinv; +bias, relu; stash row in LDS (fp32)
        float4 r;
        r.x = fmaxf(a0 * dv + b1s[4 * t + 0], 0.f);
        r.y = fmaxf(a1 * dv + b1s[4 * t + 1], 0.f);
        r.z = fmaxf(a2 * dv + b1s[4 * t + 2], 0.f);
        r.w = fmaxf(a3 * dv + b1s[4 * t + 3], 0.f);
        *(float4*)&rowbuf[wv][4 * t] = r;
    }
    // wave-local LDS: lgkmcnt ordering suffices (no cross-wave sharing)
    // GEMV row(64) @ W2(64x16): lane = (col c, k-quarter q); 16 FMA + 2 shfl
    int c = lane & 15, q = lane >> 4;
    float s = 0.f;
#pragma unroll
    for (int kk = 0; kk < 16; ++kk) {
        int k = (q << 4) + kk;
        s += rowbuf[wv][k] * W2s[k * 17 + c];
    }
    s += __shfl_xor(s, 16);
    s += __shfl_xor(s, 32);
    if (lane < 16) h2s[(size_t)gw * 16 + c] = f2bf(s * dv);
}

// ---------------- layer-2: wave per node; uint gather = 8 edges/instr; shfl idx broadcast ----------------
__global__ __launch_bounds__(256) void k_agg2f(const uint2* __restrict__ nrange,
                                               const unsigned int* __restrict__ sorted,
                                               const unsigned short* __restrict__ h2s,
                                               const float* __restrict__ dinv,
                                               const float* __restrict__ b2,
                                               float* __restrict__ out) {
    int gw = (blockIdx.x * 256 + threadIdx.x) >> 6;  // node
    if (gw >= N_NODES) return;
    int lane = threadIdx.x & 63;
    int slot = lane >> 3, t = lane & 7;  // lane covers feats [2t,2t+2) of edge-slot `slot`
    const unsigned int* h232 = (const unsigned int*)h2s;  // row = 8 x uint
    uint2 rg = nrange[gw];
    float a0 = 0.f, a1 = 0.f;
    for (unsigned int j = rg.x; j < rg.y; j += 64) {
        unsigned int cnt = rg.y - j; if (cnt > 64u) cnt = 64u;
        unsigned int idx = (unsigned)lane < cnt ? sorted[j + lane] : 0u;
        unsigned int rounds = (cnt + 7u) >> 3;
#pragma unroll 4
        for (unsigned int r = 0; r < rounds; ++r) {
            unsigned int sl = (r << 3) + (unsigned)slot;
            unsigned int myidx = (unsigned int)__shfl((int)idx, (int)sl);
            if (sl < cnt) {
                unsigned int u = h232[(size_t)myidx * 8 + t];
                a0 += lo16(u);
                a1 += hi16(u);
            }
        }
    }
    a0 += __shfl_xor(a0, 8);  a1 += __shfl_xor(a1, 8);
    a0 += __shfl_xor(a0, 16); a1 += __shfl_xor(a1, 16);
    a0 += __shfl_xor(a0, 32); a1 += __shfl_xor(a1, 32);
    if (slot == 0) {
        float dv = dinv[gw];
        float2 o;
        o.x = a0 * dv + b2[2 * t];
        o.y = a1 * dv + b2[2 * t + 1];
        *(float2*)&out[(size_t)gw * 16 + 2 * t] = o;
    }
}

static inline size_t align256(size_t x) { return (x + 255) & ~size_t(255); }

extern "C" void kernel_launch(void* const* d_in, const int* in_sizes, int n_in,
                              void* d_out, int out_size, void* d_ws, size_t ws_size,
                              hipStream_t stream) {
    const float* x  = (const float*)d_in[0];
    const int* edge = (const int*)d_in[1];
    const float* W1 = (const float*)d_in[2];
    const float* b1 = (const float*)d_in[3];
    const float* W2 = (const float*)d_in[4];
    const float* b2 = (const float*)d_in[5];
    float* out = (float*)d_out;

    const int E = in_sizes[1] / 2;
    const int* src = edge;
    const int* dst = edge + E;

    // workspace layout (~37 MB; out1 eliminated)
    char* ws = (char*)d_ws;
    size_t o = 0;
    unsigned int* gcnt    = (unsigned int*)(ws + o); o += align256((size_t)NBINS * 4);
    float* dinv           = (float*)(ws + o);        o += align256((size_t)N_NODES * 4);
    unsigned int* entries = (unsigned int*)(ws + o); o += align256((size_t)NBINS * CAPB * 4);
    unsigned int* sorted  = (unsigned int*)(ws + o); o += align256((size_t)NBINS * CAPB * 4);
    uint2* nrange         = (uint2*)(ws + o);        o += align256((size_t)N_NODES * 8);
    unsigned short* hs    = (unsigned short*)(ws + o); o += align256((size_t)N_NODES * F1 * 2);
    unsigned short* h2s   = (unsigned short*)(ws + o); o += align256((size_t)N_NODES * F2 * 2);

    hipMemsetAsync(gcnt, 0, (size_t)NBINS * 4, stream);

    int nbinblocks = (E + N_NODES + TILE - 1) / TILE;
    k_bin<<<nbinblocks, 512, 0, stream>>>(src, dst, E, gcnt, entries);
    k_csr<<<NBINS, 512, 0, stream>>>(gcnt, entries, nrange, sorted, dinv);

    // layer 1 (+ fused layer-2 projection)
    k_xw1<<<(N_NODES + 63) / 64, 256, 0, stream>>>(x, W1, dinv, hs);
    {
        int blocks = (int)(((long long)N_NODES * 64 + 255) / 256);
        k_agg1f<<<blocks, 256, 0, stream>>>(nrange, sorted, hs, dinv, b1, W2, h2s);
    }

    // layer 2
    {
        int blocks = (int)(((long long)N_NODES * 64 + 255) / 256);
        k_agg2f<<<blocks, 256, 0, stream>>>(nrange, sorted, h2s, dinv, b2, out);
    }
}

// Round 13
// 147.878 us; speedup vs baseline: 1.1048x; 1.1048x over previous
//
#include <hip/hip_runtime.h>

constexpr int N_NODES = 100000;
constexpr int F1 = 64;   // IN_DIM == HID_DIM
constexpr int F2 = 16;   // OUT_DIM
constexpr int SH = 7;                             // bin = dst >> 7
constexpr int NPB = 128;                          // nodes per bin
constexpr int NBINS = (N_NODES + NPB - 1) / NPB;  // 782
constexpr int CAPB = 2560;                        // mean 2046, +11 sigma
constexpr int TILE = 4096;                        // edges per k_bin block
constexpr int GSTRIDE = 16;                       // gcnt: one counter per 64B line

// bf16 helpers (RNE)
static __device__ __forceinline__ unsigned short f2bf(float f) {
    unsigned int u = __float_as_uint(f);
    unsigned int r = (u + 0x7fffu + ((u >> 16) & 1u)) >> 16;
    return (unsigned short)r;
}
static __device__ __forceinline__ float bf2f(unsigned short b) {
    return __uint_as_float(((unsigned int)b) << 16);
}

// ---------------- pass 1: coarse binning (block-aggregated allocation) ----------------
// 512 threads: k_bin is atomic/scatter latency-bound -> wave count matters (R10/R11 A/B)
__global__ __launch_bounds__(512) void k_bin(const int* __restrict__ src,
                                             const int* __restrict__ dst, int E,
                                             unsigned int* __restrict__ gcnt,
                                             unsigned int* __restrict__ entries) {
    __shared__ unsigned int cnt[NBINS];
    __shared__ unsigned int cur[NBINS];
    int tid = threadIdx.x;
    int base = blockIdx.x * TILE;
    int end = min(base + TILE, E);
    for (int i = tid; i < NBINS; i += 512) cnt[i] = 0;
    __syncthreads();
    for (int e = base + tid; e < end; e += 512) atomicAdd(&cnt[dst[e] >> SH], 1u);
    __syncthreads();
    for (int i = tid; i < NBINS; i += 512) {
        unsigned int c = cnt[i];
        cur[i] = (unsigned int)i * CAPB + (c ? atomicAdd(&gcnt[i * GSTRIDE], c) : 0u);
    }
    __syncthreads();
    for (int e = base + tid; e < end; e += 512) {
        int d = dst[e];
        int s = src[e];
        int bb = d >> SH;
        unsigned int p = atomicAdd(&cur[bb], 1u);
        if (p - (unsigned int)bb * CAPB < CAPB)
            entries[p] = (unsigned int)s | ((unsigned int)(d & (NPB - 1)) << 17);
    }
}

// ---------------- dinv from per-bin entry histogram ----------------
__global__ __launch_bounds__(256) void k_dinvb(const unsigned int* __restrict__ gcnt,
                                               const unsigned int* __restrict__ entries,
                                               float* __restrict__ dinv) {
    __shared__ unsigned int ncnt[NPB];
    int tid = threadIdx.x;
    int b = blockIdx.x;
    unsigned int cntE = gcnt[b * GSTRIDE]; if (cntE > CAPB) cntE = CAPB;
    unsigned int base = (unsigned int)b * CAPB;
    if (tid < NPB) ncnt[tid] = 0;
    __syncthreads();
    for (unsigned int e = tid; e < cntE; e += 256)
        atomicAdd(&ncnt[entries[base + e] >> 17], 1u);
    __syncthreads();
    if (tid < NPB) {
        int node = b * NPB + tid;
        if (node < N_NODES) dinv[node] = rsqrtf((float)(ncnt[tid] + 1u));
    }
}

// ---------------- hs = bf16((x @ W1) * dinv[row]) — register-tiled 4x4 ----------------
__global__ __launch_bounds__(256) void k_xw1(const float* __restrict__ x,
                                             const float* __restrict__ W,
                                             const float* __restrict__ dinv,
                                             unsigned short* __restrict__ hs) {
    constexpr int XS = 68;  // rb stride 4*68=272 % 32 = 16 -> only 2-way aliasing (free)
    __shared__ float Ws[64 * 64];
    __shared__ float xs[64 * XS];
    int tid = threadIdx.x;
    int r0 = blockIdx.x * 64;
    for (int i = tid; i < 1024; i += 256) {
        int k = i >> 4, c4 = (i & 15) << 2;
        *(float4*)&Ws[k * 64 + c4] = *(const float4*)&W[k * 64 + c4];
    }
    for (int i = tid; i < 1024; i += 256) {
        int rr = i >> 4, c4 = (i & 15) << 2;
        int r = r0 + rr;
        float4 v = make_float4(0.f, 0.f, 0.f, 0.f);
        if (r < N_NODES) v = *(const float4*)&x[(size_t)r * 64 + c4];
        *(float4*)&xs[rr * XS + c4] = v;
    }
    __syncthreads();
    int tx = tid & 15, ty = tid >> 4;
    int c0 = tx << 2, rb = ty << 2;
    float acc[4][4] = {};
#pragma unroll 8
    for (int k = 0; k < 64; ++k) {
        float4 w = *(float4*)&Ws[k * 64 + c0];
        float x0 = xs[(rb + 0) * XS + k];
        float x1 = xs[(rb + 1) * XS + k];
        float x2 = xs[(rb + 2) * XS + k];
        float x3 = xs[(rb + 3) * XS + k];
        acc[0][0] += x0 * w.x; acc[0][1] += x0 * w.y; acc[0][2] += x0 * w.z; acc[0][3] += x0 * w.w;
        acc[1][0] += x1 * w.x; acc[1][1] += x1 * w.y; acc[1][2] += x1 * w.z; acc[1][3] += x1 * w.w;
        acc[2][0] += x2 * w.x; acc[2][1] += x2 * w.y; acc[2][2] += x2 * w.z; acc[2][3] += x2 * w.w;
        acc[3][0] += x3 * w.x; acc[3][1] += x3 * w.y; acc[3][2] += x3 * w.z; acc[3][3] += x3 * w.w;
    }
#pragma unroll
    for (int i = 0; i < 4; ++i) {
        int r = r0 + rb + i;
        if (r >= N_NODES) break;
        float dv = dinv[r];
        ushort4 p;
        p.x = f2bf(acc[i][0] * dv);
        p.y = f2bf(acc[i][1] * dv);
        p.z = f2bf(acc[i][2] * dv);
        p.w = f2bf(acc[i][3] * dv);
        *(ushort4*)&hs[(size_t)r * 64 + c0] = p;
    }
}

// ---------------- layer-1: LDS CSR build + aggregate (block = bin, 16 waves) ----------------
__global__ __launch_bounds__(1024) void k_agg1f(const unsigned int* __restrict__ gcnt,
                                                const unsigned int* __restrict__ entries,
                                                const unsigned short* __restrict__ hs,
                                                const float* __restrict__ dinv,
                                                unsigned short* __restrict__ out1) {
    __shared__ unsigned int ncnt[NPB];
    __shared__ unsigned int noff[NPB + 1];
    __shared__ unsigned int cur[NPB];
    __shared__ unsigned int sl[CAPB];
    int tid = threadIdx.x;
    int b = blockIdx.x;
    unsigned int cntE = gcnt[b * GSTRIDE]; if (cntE > CAPB) cntE = CAPB;
    unsigned int base = (unsigned int)b * CAPB;
    if (tid < NPB) ncnt[tid] = 0;
    __syncthreads();
    for (unsigned int e = tid; e < cntE; e += 1024)
        atomicAdd(&ncnt[entries[base + e] >> 17], 1u);
    __syncthreads();
    if (tid < NPB) cur[tid] = ncnt[tid];
    __syncthreads();
    for (int ofs = 1; ofs < NPB; ofs <<= 1) {
        unsigned int v = (tid < NPB && tid >= ofs) ? cur[tid - ofs] : 0u;
        __syncthreads();
        if (tid < NPB) cur[tid] += v;
        __syncthreads();
    }
    if (tid < NPB) noff[tid + 1] = cur[tid];
    if (tid == 0) noff[0] = 0;
    __syncthreads();
    if (tid < NPB) cur[tid] = noff[tid];
    __syncthreads();
    for (unsigned int e = tid; e < cntE; e += 1024) {
        unsigned int v = entries[base + e];
        unsigned int p = atomicAdd(&cur[v >> 17], 1u);
        sl[p] = v & 0x1FFFFu;
    }
    __syncthreads();
    int wid = tid >> 6, k = tid & 63;
    for (int n = wid; n < NPB; n += 16) {
        int node = b * NPB + n;
        if (node >= N_NODES) break;  // uniform per wave
        unsigned int j = noff[n], jend = noff[n + 1];
        float acc = bf2f(hs[(size_t)node * 64 + k]);  // self-loop
        for (; j + 8 <= jend; j += 8) {
            unsigned int s0 = sl[j], s1 = sl[j + 1], s2 = sl[j + 2], s3 = sl[j + 3];
            unsigned int s4 = sl[j + 4], s5 = sl[j + 5], s6 = sl[j + 6], s7 = sl[j + 7];
            float a0 = bf2f(hs[(size_t)s0 * 64 + k]);
            float a1 = bf2f(hs[(size_t)s1 * 64 + k]);
            float a2 = bf2f(hs[(size_t)s2 * 64 + k]);
            float a3 = bf2f(hs[(size_t)s3 * 64 + k]);
            float a4 = bf2f(hs[(size_t)s4 * 64 + k]);
            float a5 = bf2f(hs[(size_t)s5 * 64 + k]);
            float a6 = bf2f(hs[(size_t)s6 * 64 + k]);
            float a7 = bf2f(hs[(size_t)s7 * 64 + k]);
            acc += ((a0 + a1) + (a2 + a3)) + ((a4 + a5) + (a6 + a7));
        }
        for (; j + 4 <= jend; j += 4) {
            unsigned int s0 = sl[j], s1 = sl[j + 1], s2 = sl[j + 2], s3 = sl[j + 3];
            float a0 = bf2f(hs[(size_t)s0 * 64 + k]);
            float a1 = bf2f(hs[(size_t)s1 * 64 + k]);
            float a2 = bf2f(hs[(size_t)s2 * 64 + k]);
            float a3 = bf2f(hs[(size_t)s3 * 64 + k]);
            acc += (a0 + a1) + (a2 + a3);
        }
        for (; j < jend; ++j) acc += bf2f(hs[(size_t)sl[j] * 64 + k]);
        out1[(size_t)node * 64 + k] = f2bf(acc * dinv[node]);
    }
}

// ---------------- h2s = bf16(relu(out1 + b1) @ W2 * dinv[row]) — register-tiled 2x4 ----------------
__global__ __launch_bounds__(256) void k_xw2(const unsigned short* __restrict__ out1,
                                             const float* __restrict__ b1,
                                             const float* __restrict__ W2,
                                             const float* __restrict__ dinv,
                                             unsigned short* __restrict__ h2s) {
    constexpr int RS = 66;
    __shared__ float Ws[64 * 16];
    __shared__ float rs[128 * RS];
    __shared__ float b1s[64];
    int tid = threadIdx.x;
    int r0 = blockIdx.x * 128;
    if (tid < 64) b1s[tid] = b1[tid];
    for (int i = tid; i < 256; i += 256)
        *(float4*)&Ws[i * 4] = *(const float4*)&W2[i * 4];
    __syncthreads();
    for (int i = tid; i < 2048; i += 256) {
        int rr = i >> 4, c4 = (i & 15) << 2;
        int r = r0 + rr;
        float v0 = 0.f, v1 = 0.f, v2 = 0.f, v3 = 0.f;
        if (r < N_NODES) {
            ushort4 u = *(const ushort4*)&out1[(size_t)r * 64 + c4];
            v0 = fmaxf(bf2f(u.x) + b1s[c4 + 0], 0.f);
            v1 = fmaxf(bf2f(u.y) + b1s[c4 + 1], 0.f);
            v2 = fmaxf(bf2f(u.z) + b1s[c4 + 2], 0.f);
            v3 = fmaxf(bf2f(u.w) + b1s[c4 + 3], 0.f);
        }
        float* pp = &rs[rr * RS + c4];
        pp[0] = v0; pp[1] = v1; pp[2] = v2; pp[3] = v3;
    }
    __syncthreads();
    int tx = tid & 3, ty = tid >> 2;
    int c0 = tx << 2, rb = ty << 1;
    float acc[2][4] = {};
#pragma unroll 8
    for (int k = 0; k < 64; ++k) {
        float4 w = *(float4*)&Ws[k * 16 + c0];
        float x0 = rs[(rb + 0) * RS + k];
        float x1 = rs[(rb + 1) * RS + k];
        acc[0][0] += x0 * w.x; acc[0][1] += x0 * w.y; acc[0][2] += x0 * w.z; acc[0][3] += x0 * w.w;
        acc[1][0] += x1 * w.x; acc[1][1] += x1 * w.y; acc[1][2] += x1 * w.z; acc[1][3] += x1 * w.w;
    }
#pragma unroll
    for (int i = 0; i < 2; ++i) {
        int r = r0 + rb + i;
        if (r >= N_NODES) break;
        float dv = dinv[r];
        ushort4 p;
        p.x = f2bf(acc[i][0] * dv);
        p.y = f2bf(acc[i][1] * dv);
        p.z = f2bf(acc[i][2] * dv);
        p.w = f2bf(acc[i][3] * dv);
        *(ushort4*)&h2s[(size_t)r * 16 + c0] = p;
    }
}

// ---------------- layer-2: LDS CSR build + aggregate (16 feats x 4 edge slots) ----------------
__global__ __launch_bounds__(1024) void k_agg2f(const unsigned int* __restrict__ gcnt,
                                                const unsigned int* __restrict__ entries,
                                                const unsigned short* __restrict__ h2s,
                                                const float* __restrict__ dinv,
                                                const float* __restrict__ b2,
                                                float* __restrict__ out) {
    __shared__ unsigned int ncnt[NPB];
    __shared__ unsigned int noff[NPB + 1];
    __shared__ unsigned int cur[NPB];
    __shared__ unsigned int sl[CAPB];
    int tid = threadIdx.x;
    int b = blockIdx.x;
    unsigned int cntE = gcnt[b * GSTRIDE]; if (cntE > CAPB) cntE = CAPB;
    unsigned int base = (unsigned int)b * CAPB;
    if (tid < NPB) ncnt[tid] = 0;
    __syncthreads();
    for (unsigned int e = tid; e < cntE; e += 1024)
        atomicAdd(&ncnt[entries[base + e] >> 17], 1u);
    __syncthreads();
    if (tid < NPB) cur[tid] = ncnt[tid];
    __syncthreads();
    for (int ofs = 1; ofs < NPB; ofs <<= 1) {
        unsigned int v = (tid < NPB && tid >= ofs) ? cur[tid - ofs] : 0u;
        __syncthreads();
        if (tid < NPB) cur[tid] += v;
        __syncthreads();
    }
    if (tid < NPB) noff[tid + 1] = cur[tid];
    if (tid == 0) noff[0] = 0;
    __syncthreads();
    if (tid < NPB) cur[tid] = noff[tid];
    __syncthreads();
    for (unsigned int e = tid; e < cntE; e += 1024) {
        unsigned int v = entries[base + e];
        unsigned int p = atomicAdd(&cur[v >> 17], 1u);
        sl[p] = v & 0x1FFFFu;
    }
    __syncthreads();
    int wid = tid >> 6, lane = tid & 63;
    int k = lane & 15, esub = lane >> 4;
    for (int n = wid; n < NPB; n += 16) {
        int node = b * NPB + n;
        if (node >= N_NODES) break;  // uniform per wave
        unsigned int j0 = noff[n], jend = noff[n + 1];
        float acc = 0.0f;
        unsigned int j = j0 + esub;
        for (; j + 4 < jend; j += 8) {
            float a = bf2f(h2s[(size_t)sl[j] * 16 + k]);
            float c = bf2f(h2s[(size_t)sl[j + 4] * 16 + k]);
            acc += a + c;
        }
        if (j < jend) acc += bf2f(h2s[(size_t)sl[j] * 16 + k]);
        acc += __shfl_xor(acc, 16);
        acc += __shfl_xor(acc, 32);
        if (lane < 16)
            out[(size_t)node * 16 + k] = (acc + bf2f(h2s[(size_t)node * 16 + k])) * dinv[node] + b2[k];
    }
}

static inline size_t align256(size_t x) { return (x + 255) & ~size_t(255); }

extern "C" void kernel_launch(void* const* d_in, const int* in_sizes, int n_in,
                              void* d_out, int out_size, void* d_ws, size_t ws_size,
                              hipStream_t stream) {
    const float* x  = (const float*)d_in[0];
    const int* edge = (const int*)d_in[1];
    const float* W1 = (const float*)d_in[2];
    const float* b1 = (const float*)d_in[3];
    const float* W2 = (const float*)d_in[4];
    const float* b2 = (const float*)d_in[5];
    float* out = (float*)d_out;

    const int E = in_sizes[1] / 2;
    const int* src = edge;
    const int* dst = edge + E;

    // workspace layout (~37 MB)
    char* ws = (char*)d_ws;
    size_t o = 0;
    unsigned int* gcnt    = (unsigned int*)(ws + o); o += align256((size_t)NBINS * GSTRIDE * 4);
    float* dinv           = (float*)(ws + o);        o += align256((size_t)N_NODES * 4);
    unsigned int* entries = (unsigned int*)(ws + o); o += align256((size_t)NBINS * CAPB * 4);
    unsigned short* hs    = (unsigned short*)(ws + o); o += align256((size_t)N_NODES * F1 * 2);
    unsigned short* out1  = (unsigned short*)(ws + o); o += align256((size_t)N_NODES * F1 * 2);
    unsigned short* h2s   = (unsigned short*)(ws + o); o += align256((size_t)N_NODES * F2 * 2);

    hipMemsetAsync(gcnt, 0, (size_t)NBINS * GSTRIDE * 4, stream);

    k_bin<<<(E + TILE - 1) / TILE, 512, 0, stream>>>(src, dst, E, gcnt, entries);
    k_dinvb<<<NBINS, 256, 0, stream>>>(gcnt, entries, dinv);

    // layer 1
    k_xw1<<<(N_NODES + 63) / 64, 256, 0, stream>>>(x, W1, dinv, hs);
    k_agg1f<<<NBINS, 1024, 0, stream>>>(gcnt, entries, hs, dinv, out1);

    // layer 2
    k_xw2<<<(N_NODES + 127) / 128, 256, 0, stream>>>(out1, b1, W2, dinv, h2s);
    k_agg2f<<<NBINS, 1024, 0, stream>>>(gcnt, entries, h2s, dinv, b2, out);
}

// Round 14
// 144.415 us; speedup vs baseline: 1.1313x; 1.0240x over previous
//
#include <hip/hip_runtime.h>

constexpr int N_NODES = 100000;
constexpr int F1 = 64;   // IN_DIM == HID_DIM
constexpr int F2 = 16;   // OUT_DIM
constexpr int SH = 7;                             // bin = dst >> 7
constexpr int NPB = 128;                          // nodes per bin
constexpr int NBINS = (N_NODES + NPB - 1) / NPB;  // 782
constexpr int CAPB = 2560;                        // mean 2046, +11 sigma
constexpr int TILE = 4096;                        // edges per k_bin block
constexpr int GSTRIDE = 16;                       // gcnt: one counter per 64B line

// bf16 helpers (RNE)
static __device__ __forceinline__ unsigned short f2bf(float f) {
    unsigned int u = __float_as_uint(f);
    unsigned int r = (u + 0x7fffu + ((u >> 16) & 1u)) >> 16;
    return (unsigned short)r;
}
static __device__ __forceinline__ float bf2f(unsigned short b) {
    return __uint_as_float(((unsigned int)b) << 16);
}

// ---------------- pass 1: coarse binning (block-aggregated allocation) ----------------
__global__ __launch_bounds__(512) void k_bin(const int* __restrict__ src,
                                             const int* __restrict__ dst, int E,
                                             unsigned int* __restrict__ gcnt,
                                             unsigned int* __restrict__ entries) {
    __shared__ unsigned int cnt[NBINS];
    __shared__ unsigned int cur[NBINS];
    int tid = threadIdx.x;
    int base = blockIdx.x * TILE;
    int end = min(base + TILE, E);
    for (int i = tid; i < NBINS; i += 512) cnt[i] = 0;
    __syncthreads();
    for (int e = base + tid; e < end; e += 512) atomicAdd(&cnt[dst[e] >> SH], 1u);
    __syncthreads();
    for (int i = tid; i < NBINS; i += 512) {
        unsigned int c = cnt[i];
        cur[i] = (unsigned int)i * CAPB + (c ? atomicAdd(&gcnt[i * GSTRIDE], c) : 0u);
    }
    __syncthreads();
    for (int e = base + tid; e < end; e += 512) {
        int d = dst[e];
        int s = src[e];
        int bb = d >> SH;
        unsigned int p = atomicAdd(&cur[bb], 1u);
        if (p - (unsigned int)bb * CAPB < CAPB)
            entries[p] = (unsigned int)s | ((unsigned int)(d & (NPB - 1)) << 17);
    }
}

// ---------------- hs = bf16((x @ W1) * dinv[row]); block = bin (128 rows), fused degree->dinv ----------------
__global__ __launch_bounds__(512) void k_xw1(const float* __restrict__ x,
                                             const float* __restrict__ W,
                                             const unsigned int* __restrict__ gcnt,
                                             const unsigned int* __restrict__ entries,
                                             float* __restrict__ dinv,
                                             unsigned short* __restrict__ hs) {
    constexpr int XS = 68;  // 2-way bank aliasing only (free)
    __shared__ float Ws[64 * 64];
    __shared__ float xs[128 * XS];
    __shared__ unsigned int ncnt[NPB];
    __shared__ float dinvs[NPB];
    int tid = threadIdx.x;
    int b = blockIdx.x;
    int r0 = b * NPB;
    // stage W (64x64) and x tile (128x64)
    for (int i = tid; i < 1024; i += 512) {
        int k = i >> 4, c4 = (i & 15) << 2;
        *(float4*)&Ws[k * 64 + c4] = *(const float4*)&W[k * 64 + c4];
    }
    for (int i = tid; i < 2048; i += 512) {
        int rr = i >> 4, c4 = (i & 15) << 2;
        int r = r0 + rr;
        float4 v = make_float4(0.f, 0.f, 0.f, 0.f);
        if (r < N_NODES) v = *(const float4*)&x[(size_t)r * 64 + c4];
        *(float4*)&xs[rr * XS + c4] = v;
    }
    if (tid < NPB) ncnt[tid] = 0;
    __syncthreads();
    // per-node degree from this bin's entries -> dinv
    unsigned int cntE = gcnt[b * GSTRIDE]; if (cntE > CAPB) cntE = CAPB;
    unsigned int ebase = (unsigned int)b * CAPB;
    for (unsigned int e = tid; e < cntE; e += 512)
        atomicAdd(&ncnt[entries[ebase + e] >> 17], 1u);
    __syncthreads();
    if (tid < NPB) {
        int node = r0 + tid;
        float dv = rsqrtf((float)(ncnt[tid] + 1u));
        dinvs[tid] = dv;
        if (node < N_NODES) dinv[node] = dv;
    }
    __syncthreads();
    int tx = tid & 15, ty = tid >> 4;  // ty 0..31
    int c0 = tx << 2, rb = ty << 2;    // rb 0..124
    float acc[4][4] = {};
#pragma unroll 8
    for (int k = 0; k < 64; ++k) {
        float4 w = *(float4*)&Ws[k * 64 + c0];
        float x0 = xs[(rb + 0) * XS + k];
        float x1 = xs[(rb + 1) * XS + k];
        float x2 = xs[(rb + 2) * XS + k];
        float x3 = xs[(rb + 3) * XS + k];
        acc[0][0] += x0 * w.x; acc[0][1] += x0 * w.y; acc[0][2] += x0 * w.z; acc[0][3] += x0 * w.w;
        acc[1][0] += x1 * w.x; acc[1][1] += x1 * w.y; acc[1][2] += x1 * w.z; acc[1][3] += x1 * w.w;
        acc[2][0] += x2 * w.x; acc[2][1] += x2 * w.y; acc[2][2] += x2 * w.z; acc[2][3] += x2 * w.w;
        acc[3][0] += x3 * w.x; acc[3][1] += x3 * w.y; acc[3][2] += x3 * w.z; acc[3][3] += x3 * w.w;
    }
#pragma unroll
    for (int i = 0; i < 4; ++i) {
        int r = r0 + rb + i;
        if (r >= N_NODES) break;
        float dv = dinvs[rb + i];
        ushort4 p;
        p.x = f2bf(acc[i][0] * dv);
        p.y = f2bf(acc[i][1] * dv);
        p.z = f2bf(acc[i][2] * dv);
        p.w = f2bf(acc[i][3] * dv);
        *(ushort4*)&hs[(size_t)r * 64 + c0] = p;
    }
}

// ---------------- layer-1: LDS CSR build + aggregate; saves sorted CSR for agg2 ----------------
__global__ __launch_bounds__(1024) void k_agg1f(const unsigned int* __restrict__ gcnt,
                                                unsigned int* __restrict__ entries,  // overwritten with sorted
                                                unsigned int* __restrict__ noffg,
                                                const unsigned short* __restrict__ hs,
                                                const float* __restrict__ dinv,
                                                unsigned short* __restrict__ out1) {
    __shared__ unsigned int ncnt[NPB];
    __shared__ unsigned int noff[NPB + 1];
    __shared__ unsigned int cur[NPB];
    __shared__ unsigned int sl[CAPB];
    int tid = threadIdx.x;
    int b = blockIdx.x;
    unsigned int cntE = gcnt[b * GSTRIDE]; if (cntE > CAPB) cntE = CAPB;
    unsigned int base = (unsigned int)b * CAPB;
    if (tid < NPB) ncnt[tid] = 0;
    __syncthreads();
    for (unsigned int e = tid; e < cntE; e += 1024)
        atomicAdd(&ncnt[entries[base + e] >> 17], 1u);
    __syncthreads();
    if (tid < NPB) cur[tid] = ncnt[tid];
    __syncthreads();
    for (int ofs = 1; ofs < NPB; ofs <<= 1) {
        unsigned int v = (tid < NPB && tid >= ofs) ? cur[tid - ofs] : 0u;
        __syncthreads();
        if (tid < NPB) cur[tid] += v;
        __syncthreads();
    }
    if (tid < NPB) noff[tid + 1] = cur[tid];
    if (tid == 0) noff[0] = 0;
    __syncthreads();
    if (tid < NPB) cur[tid] = noff[tid];
    __syncthreads();
    for (unsigned int e = tid; e < cntE; e += 1024) {
        unsigned int v = entries[base + e];
        unsigned int p = atomicAdd(&cur[v >> 17], 1u);
        sl[p] = v & 0x1FFFFu;
    }
    __syncthreads();
    // persist sorted CSR (entries overwritten in place; safe after barrier)
    for (unsigned int e = tid; e < cntE; e += 1024) entries[base + e] = sl[e];
    if (tid <= NPB) noffg[b * (NPB + 1) + tid] = noff[tid];
    int wid = tid >> 6, k = tid & 63;
    for (int n = wid; n < NPB; n += 16) {
        int node = b * NPB + n;
        if (node >= N_NODES) break;  // uniform per wave
        unsigned int j = noff[n], jend = noff[n + 1];
        float acc = bf2f(hs[(size_t)node * 64 + k]);  // self-loop
        for (; j + 8 <= jend; j += 8) {
            unsigned int s0 = sl[j], s1 = sl[j + 1], s2 = sl[j + 2], s3 = sl[j + 3];
            unsigned int s4 = sl[j + 4], s5 = sl[j + 5], s6 = sl[j + 6], s7 = sl[j + 7];
            float a0 = bf2f(hs[(size_t)s0 * 64 + k]);
            float a1 = bf2f(hs[(size_t)s1 * 64 + k]);
            float a2 = bf2f(hs[(size_t)s2 * 64 + k]);
            float a3 = bf2f(hs[(size_t)s3 * 64 + k]);
            float a4 = bf2f(hs[(size_t)s4 * 64 + k]);
            float a5 = bf2f(hs[(size_t)s5 * 64 + k]);
            float a6 = bf2f(hs[(size_t)s6 * 64 + k]);
            float a7 = bf2f(hs[(size_t)s7 * 64 + k]);
            acc += ((a0 + a1) + (a2 + a3)) + ((a4 + a5) + (a6 + a7));
        }
        for (; j + 4 <= jend; j += 4) {
            unsigned int s0 = sl[j], s1 = sl[j + 1], s2 = sl[j + 2], s3 = sl[j + 3];
            float a0 = bf2f(hs[(size_t)s0 * 64 + k]);
            float a1 = bf2f(hs[(size_t)s1 * 64 + k]);
            float a2 = bf2f(hs[(size_t)s2 * 64 + k]);
            float a3 = bf2f(hs[(size_t)s3 * 64 + k]);
            acc += (a0 + a1) + (a2 + a3);
        }
        for (; j < jend; ++j) acc += bf2f(hs[(size_t)sl[j] * 64 + k]);
        out1[(size_t)node * 64 + k] = f2bf(acc * dinv[node]);
    }
}

// ---------------- h2s = bf16(relu(out1 + b1) @ W2 * dinv[row]) — register-tiled 2x4 ----------------
__global__ __launch_bounds__(256) void k_xw2(const unsigned short* __restrict__ out1,
                                             const float* __restrict__ b1,
                                             const float* __restrict__ W2,
                                             const float* __restrict__ dinv,
                                             unsigned short* __restrict__ h2s) {
    constexpr int RS = 66;
    __shared__ float Ws[64 * 16];
    __shared__ float rs[128 * RS];
    __shared__ float b1s[64];
    int tid = threadIdx.x;
    int r0 = blockIdx.x * 128;
    if (tid < 64) b1s[tid] = b1[tid];
    for (int i = tid; i < 256; i += 256)
        *(float4*)&Ws[i * 4] = *(const float4*)&W2[i * 4];
    __syncthreads();
    for (int i = tid; i < 2048; i += 256) {
        int rr = i >> 4, c4 = (i & 15) << 2;
        int r = r0 + rr;
        float v0 = 0.f, v1 = 0.f, v2 = 0.f, v3 = 0.f;
        if (r < N_NODES) {
            ushort4 u = *(const ushort4*)&out1[(size_t)r * 64 + c4];
            v0 = fmaxf(bf2f(u.x) + b1s[c4 + 0], 0.f);
            v1 = fmaxf(bf2f(u.y) + b1s[c4 + 1], 0.f);
            v2 = fmaxf(bf2f(u.z) + b1s[c4 + 2], 0.f);
            v3 = fmaxf(bf2f(u.w) + b1s[c4 + 3], 0.f);
        }
        float* pp = &rs[rr * RS + c4];
        pp[0] = v0; pp[1] = v1; pp[2] = v2; pp[3] = v3;
    }
    __syncthreads();
    int tx = tid & 3, ty = tid >> 2;
    int c0 = tx << 2, rb = ty << 1;
    float acc[2][4] = {};
#pragma unroll 8
    for (int k = 0; k < 64; ++k) {
        float4 w = *(float4*)&Ws[k * 16 + c0];
        float x0 = rs[(rb + 0) * RS + k];
        float x1 = rs[(rb + 1) * RS + k];
        acc[0][0] += x0 * w.x; acc[0][1] += x0 * w.y; acc[0][2] += x0 * w.z; acc[0][3] += x0 * w.w;
        acc[1][0] += x1 * w.x; acc[1][1] += x1 * w.y; acc[1][2] += x1 * w.z; acc[1][3] += x1 * w.w;
    }
#pragma unroll
    for (int i = 0; i < 2; ++i) {
        int r = r0 + rb + i;
        if (r >= N_NODES) break;
        float dv = dinv[r];
        ushort4 p;
        p.x = f2bf(acc[i][0] * dv);
        p.y = f2bf(acc[i][1] * dv);
        p.z = f2bf(acc[i][2] * dv);
        p.w = f2bf(acc[i][3] * dv);
        *(ushort4*)&h2s[(size_t)r * 16 + c0] = p;
    }
}

// ---------------- layer-2: consume saved CSR (no rebuild); 16 feats x 4 edge slots ----------------
__global__ __launch_bounds__(1024) void k_agg2f(const unsigned int* __restrict__ gcnt,
                                                const unsigned int* __restrict__ sorted,  // = entries (sorted)
                                                const unsigned int* __restrict__ noffg,
                                                const unsigned short* __restrict__ h2s,
                                                const float* __restrict__ dinv,
                                                const float* __restrict__ b2,
                                                float* __restrict__ out) {
    __shared__ unsigned int noff[NPB + 1];
    __shared__ unsigned int sl[CAPB];
    int tid = threadIdx.x;
    int b = blockIdx.x;
    unsigned int cntE = gcnt[b * GSTRIDE]; if (cntE > CAPB) cntE = CAPB;
    unsigned int base = (unsigned int)b * CAPB;
    if (tid <= NPB) noff[tid] = noffg[b * (NPB + 1) + tid];
    for (unsigned int e = tid; e < cntE; e += 1024) sl[e] = sorted[base + e];
    __syncthreads();
    int wid = tid >> 6, lane = tid & 63;
    int k = lane & 15, esub = lane >> 4;
    for (int n = wid; n < NPB; n += 16) {
        int node = b * NPB + n;
        if (node >= N_NODES) break;  // uniform per wave
        unsigned int j0 = noff[n], jend = noff[n + 1];
        float acc = 0.0f;
        unsigned int j = j0 + esub;
        for (; j + 4 < jend; j += 8) {
            float a = bf2f(h2s[(size_t)sl[j] * 16 + k]);
            float c = bf2f(h2s[(size_t)sl[j + 4] * 16 + k]);
            acc += a + c;
        }
        if (j < jend) acc += bf2f(h2s[(size_t)sl[j] * 16 + k]);
        acc += __shfl_xor(acc, 16);
        acc += __shfl_xor(acc, 32);
        if (lane < 16)
            out[(size_t)node * 16 + k] = (acc + bf2f(h2s[(size_t)node * 16 + k])) * dinv[node] + b2[k];
    }
}

static inline size_t align256(size_t x) { return (x + 255) & ~size_t(255); }

extern "C" void kernel_launch(void* const* d_in, const int* in_sizes, int n_in,
                              void* d_out, int out_size, void* d_ws, size_t ws_size,
                              hipStream_t stream) {
    const float* x  = (const float*)d_in[0];
    const int* edge = (const int*)d_in[1];
    const float* W1 = (const float*)d_in[2];
    const float* b1 = (const float*)d_in[3];
    const float* W2 = (const float*)d_in[4];
    const float* b2 = (const float*)d_in[5];
    float* out = (float*)d_out;

    const int E = in_sizes[1] / 2;
    const int* src = edge;
    const int* dst = edge + E;

    // workspace layout (~38 MB)
    char* ws = (char*)d_ws;
    size_t o = 0;
    unsigned int* gcnt    = (unsigned int*)(ws + o); o += align256((size_t)NBINS * GSTRIDE * 4);
    float* dinv           = (float*)(ws + o);        o += align256((size_t)N_NODES * 4);
    unsigned int* entries = (unsigned int*)(ws + o); o += align256((size_t)NBINS * CAPB * 4);
    unsigned int* noffg   = (unsigned int*)(ws + o); o += align256((size_t)NBINS * (NPB + 1) * 4);
    unsigned short* hs    = (unsigned short*)(ws + o); o += align256((size_t)N_NODES * F1 * 2);
    unsigned short* out1  = (unsigned short*)(ws + o); o += align256((size_t)N_NODES * F1 * 2);
    unsigned short* h2s   = (unsigned short*)(ws + o); o += align256((size_t)N_NODES * F2 * 2);

    hipMemsetAsync(gcnt, 0, (size_t)NBINS * GSTRIDE * 4, stream);

    k_bin<<<(E + TILE - 1) / TILE, 512, 0, stream>>>(src, dst, E, gcnt, entries);

    // layer 1 (dinv fused into k_xw1; agg1 persists sorted CSR)
    k_xw1<<<NBINS, 512, 0, stream>>>(x, W1, gcnt, entries, dinv, hs);
    k_agg1f<<<NBINS, 1024, 0, stream>>>(gcnt, entries, noffg, hs, dinv, out1);

    // layer 2 (agg2 consumes saved CSR)
    k_xw2<<<(N_NODES + 127) / 128, 256, 0, stream>>>(out1, b1, W2, dinv, h2s);
    k_agg2f<<<NBINS, 1024, 0, stream>>>(gcnt, entries, noffg, h2s, dinv, b2, out);
}